// Round 1
// baseline (184.196 us; speedup 1.0000x reference)
//
#include <hip/hip_runtime.h>
#include <hip/hip_fp16.h>

typedef __bf16 bf16x8 __attribute__((ext_vector_type(8)));
typedef float floatx4 __attribute__((ext_vector_type(4)));

constexpr int Ndim = 8192;
constexpr int Kdim = 8192;
constexpr int BM = 64, BN = 64, BK = 64;
constexpr int NT = Kdim / BK;      // 128 K-steps
constexpr int KB = Kdim / 256;     // 32 Q4_K blocks per weight row

union U8 { unsigned int u[4]; bf16x8 v; };

struct BStage {
  unsigned int q[8];                 // 8 qs byte-values (each 0..255)
  unsigned short dbits, dmbits;      // fp16 bit patterns of d, dmin
  unsigned int sd[2], sm[2], smd[2]; // scale bytes for the 2 sub-blocks
};

// swizzled short-index for (row, 16B-chunk): breaks the 128B-row bank aliasing
__device__ __forceinline__ int swz(int row, int ch) {
  return row * 64 + ((ch ^ (row & 7)) << 3);
}

// pack two f32 -> two bf16 (round-half-up) in one word via v_perm
__device__ __forceinline__ unsigned int pk(float a, float b) {
  unsigned int ua = __float_as_uint(a) + 0x8000u;
  unsigned int ub = __float_as_uint(b) + 0x8000u;
  return __builtin_amdgcn_perm(ub, ua, 0x07060302u);
}

__global__ __launch_bounds__(256, 2)
void q4k_gemm(const float* __restrict__ x, const int* __restrict__ qw,
              const float* __restrict__ bias, float* __restrict__ out)
{
  __shared__ unsigned short Ab[2][BM * BK];   // 8 KB each
  __shared__ unsigned short Bb[2][BN * BK];

  const int tid  = threadIdx.x;
  const int bid  = blockIdx.x;
  // XCD-aware: xcd = bid&7 (hw round-robin); cluster one M-tile per XCD pair
  const int xcd  = bid & 7;
  const int idx  = bid >> 3;                  // 0..63
  const int m0   = (xcd >> 1) * BM;           // 4 M-tiles
  const int n0   = (((xcd & 1) << 6) | idx) * BN;  // 128 N-tiles

  const int sr = tid >> 2;   // staging row 0..63
  const int sq = tid & 3;    // staging quarter

  const bool packed = ((const unsigned int*)qw)[0] > 255u;  // uint8-layout hedge

  const float* aptr = x + (m0 + sr) * Kdim + sq * 16;
  const int nrow = n0 + sr;

  const int lane = tid & 63;
  const int wave = tid >> 6;
  const int wm = (wave >> 1) << 5;
  const int wn = (wave & 1) << 5;
  const int fr = lane & 15;
  const int fq = lane >> 4;

  floatx4 acc[2][2] = {};

  float4 av[4];
  BStage bs;

  auto gload = [&](int t) {
    const int k0 = t * BK;
    const float4* ap = (const float4*)(aptr + k0);
    av[0] = ap[0]; av[1] = ap[1]; av[2] = ap[2]; av[3] = ap[3];
    const int blk = nrow * KB + (k0 >> 8);
    const int c   = (k0 >> 6) & 3;
    const int jlo = (2 * c) & 3;               // 0 or 2
    if (!packed) {
      const int* bp = qw + blk * 144;
      uint4 ddm = *(const uint4*)bp;
      bs.dbits  = (unsigned short)((ddm.x & 255u) | ((ddm.y & 255u) << 8));
      bs.dmbits = (unsigned short)((ddm.z & 255u) | ((ddm.w & 255u) << 8));
      uint2 s0 = *(const uint2*)(bp + 4 + jlo);
      uint2 s1 = *(const uint2*)(bp + 8 + jlo);
      uint2 s2 = *(const uint2*)(bp + 12 + jlo);
      bs.sd[0]=s0.x; bs.sd[1]=s0.y; bs.sm[0]=s1.x; bs.sm[1]=s1.y;
      bs.smd[0]=s2.x; bs.smd[1]=s2.y;
      const uint4* qp = (const uint4*)(bp + 16 + c * 32 + sq * 8);
      uint4 q0 = qp[0], q1 = qp[1];
      bs.q[0]=q0.x; bs.q[1]=q0.y; bs.q[2]=q0.z; bs.q[3]=q0.w;
      bs.q[4]=q1.x; bs.q[5]=q1.y; bs.q[6]=q1.z; bs.q[7]=q1.w;
    } else {
      const unsigned char* bp = (const unsigned char*)qw + blk * 144;
      uint4 meta = *(const uint4*)bp;
      bs.dbits  = (unsigned short)(meta.x & 0xFFFFu);
      bs.dmbits = (unsigned short)(meta.x >> 16);
      bs.sd[0] = (meta.y >> (8*jlo)) & 255u;  bs.sd[1] = (meta.y >> (8*jlo+8)) & 255u;
      bs.sm[0] = (meta.z >> (8*jlo)) & 255u;  bs.sm[1] = (meta.z >> (8*jlo+8)) & 255u;
      bs.smd[0]= (meta.w >> (8*jlo)) & 255u;  bs.smd[1]= (meta.w >> (8*jlo+8)) & 255u;
      uint2 qv = *(const uint2*)(bp + 16 + c * 32 + sq * 8);
      bs.q[0]=qv.x & 255u; bs.q[1]=(qv.x>>8)&255u; bs.q[2]=(qv.x>>16)&255u; bs.q[3]=qv.x>>24;
      bs.q[4]=qv.y & 255u; bs.q[5]=(qv.y>>8)&255u; bs.q[6]=(qv.y>>16)&255u; bs.q[7]=qv.y>>24;
    }
  };

  auto stage = [&](int t, int buf) {
    // ---- A tile: 16 f32 -> bf16, chunks 2sq, 2sq+1 of row sr ----
    unsigned int aw[8];
    #pragma unroll
    for (int i = 0; i < 4; ++i) {
      aw[2*i]   = pk(av[i].x, av[i].y);
      aw[2*i+1] = pk(av[i].z, av[i].w);
    }
    U8 ua0, ua1;
    ua0.u[0]=aw[0]; ua0.u[1]=aw[1]; ua0.u[2]=aw[2]; ua0.u[3]=aw[3];
    ua1.u[0]=aw[4]; ua1.u[1]=aw[5]; ua1.u[2]=aw[6]; ua1.u[3]=aw[7];
    *(bf16x8*)&Ab[buf][swz(sr, 2*sq)]   = ua0.v;
    *(bf16x8*)&Ab[buf][swz(sr, 2*sq+1)] = ua1.v;

    // ---- B tile: dequant 8 qs bytes -> 16 weights (both nibbles) ----
    const int k0 = t * BK;
    const int c = (k0 >> 6) & 3;
    const float d  = __half2float(__ushort_as_half(bs.dbits));
    const float dm = __half2float(__ushort_as_half(bs.dmbits));
    float dl[2], ml[2];
    #pragma unroll
    for (int g = 0; g < 2; ++g) {
      unsigned int sc, mn;
      if (c < 2) {  // sub-block i = 2c+g < 4  (uniform per K-step)
        sc = bs.sd[g] & 63u;
        mn = bs.sm[g] & 63u;
      } else {
        sc = (bs.smd[g] & 15u) | ((bs.sd[g] >> 2) & 48u);
        mn = (bs.smd[g] >> 4)  | ((bs.sm[g] >> 2) & 48u);
      }
      dl[g] = d * (float)sc;
      ml[g] = dm * (float)mn;
    }
    float wlo[8], whi[8];
    #pragma unroll
    for (int z = 0; z < 8; ++z) {
      wlo[z] = dl[0] * (float)(bs.q[z] & 15u) - ml[0];
      whi[z] = dl[1] * (float)(bs.q[z] >> 4)  - ml[1];  // bytes are <=255: no mask needed
    }
    U8 ub0, ub1;
    #pragma unroll
    for (int p = 0; p < 4; ++p) {
      ub0.u[p] = pk(wlo[2*p], wlo[2*p+1]);
      ub1.u[p] = pk(whi[2*p], whi[2*p+1]);
    }
    // low nibbles -> k chunk sq, high nibbles -> k chunk sq+4 (k offset +32)
    *(bf16x8*)&Bb[buf][swz(sr, sq)]     = ub0.v;
    *(bf16x8*)&Bb[buf][swz(sr, sq + 4)] = ub1.v;
  };

  gload(0);
  stage(0, 0);
  __syncthreads();

  int cur = 0;
  for (int t = 0; t < NT; ++t) {
    if (t + 1 < NT) gload(t + 1);   // issue global loads early; overlap MFMA

    #pragma unroll
    for (int kk = 0; kk < 2; ++kk) {
      bf16x8 af[2], bfr[2];
      #pragma unroll
      for (int mi = 0; mi < 2; ++mi)
        af[mi] = *(const bf16x8*)&Ab[cur][swz(wm + mi*16 + fr, kk*4 + fq)];
      #pragma unroll
      for (int ni = 0; ni < 2; ++ni)
        bfr[ni] = *(const bf16x8*)&Bb[cur][swz(wn + ni*16 + fr, kk*4 + fq)];
      #pragma unroll
      for (int mi = 0; mi < 2; ++mi)
        #pragma unroll
        for (int ni = 0; ni < 2; ++ni)
          acc[mi][ni] = __builtin_amdgcn_mfma_f32_16x16x32_bf16(
              af[mi], bfr[ni], acc[mi][ni], 0, 0, 0);
    }

    if (t + 1 < NT) stage(t + 1, cur ^ 1);
    __syncthreads();
    cur ^= 1;
  }

  // epilogue: C/D layout col=lane&15, row=(lane>>4)*4+reg  [m89-verified]
  #pragma unroll
  for (int mi = 0; mi < 2; ++mi) {
    #pragma unroll
    for (int ni = 0; ni < 2; ++ni) {
      const int gn = n0 + wn + ni*16 + fr;
      const float bv = bias[gn];
      #pragma unroll
      for (int jj = 0; jj < 4; ++jj) {
        const int gm = m0 + wm + mi*16 + fq*4 + jj;
        out[gm * Ndim + gn] = acc[mi][ni][jj] + bv;
      }
    }
  }
}

extern "C" void kernel_launch(void* const* d_in, const int* in_sizes, int n_in,
                              void* d_out, int out_size, void* d_ws, size_t ws_size,
                              hipStream_t stream) {
  const float* x    = (const float*)d_in[0];
  const int*   qw   = (const int*)d_in[1];
  const float* bias = (const float*)d_in[2];
  float* out = (float*)d_out;
  q4k_gemm<<<512, 256, 0, stream>>>(x, qw, bias, out);
}

// Round 2
// 110.996 us; speedup vs baseline: 1.6595x; 1.6595x over previous
//
#include <hip/hip_runtime.h>
#include <hip/hip_fp16.h>

typedef __bf16 bf16x8 __attribute__((ext_vector_type(8)));
typedef float floatx4 __attribute__((ext_vector_type(4)));
typedef unsigned int uint;
typedef unsigned short ushort;

constexpr int Mdim = 256;
constexpr int Ndim = 8192;
constexpr int Kdim = 8192;
constexpr int BM = 64, BN = 64, BK = 128;
constexpr int NT = Kdim / BK;      // 64 K-steps
constexpr int KB = Kdim / 256;     // 32 Q4_K blocks per weight row

union U8 { uint u[4]; bf16x8 v; };

// swizzled ushort-index for (row, 16B-chunk); 16 chunks/row at BK=128
__device__ __forceinline__ int swz(int row, int ch) {
  return row * 128 + ((ch ^ (row & 15)) << 3);
}

// pack two f32 -> two bf16 (round-half-up) in one word via v_perm
__device__ __forceinline__ uint pk(float a, float b) {
  uint ua = __float_as_uint(a) + 0x8000u;
  uint ub = __float_as_uint(b) + 0x8000u;
  return __builtin_amdgcn_perm(ub, ua, 0x07060302u);
}

__device__ __forceinline__ void glds16(const void* g, void* l) {
  __builtin_amdgcn_global_load_lds(
      (const __attribute__((address_space(1))) uint*)g,
      (__attribute__((address_space(3))) uint*)l, 16, 0, 0);
}

struct BSet {
  uint4 q[4];        // 16 widened qs bytes
  uint4 ddm;         // d/dmin byte ints
  uint2 D, M, X;     // scale byte pairs
  float4 av[8];      // fallback-only: 32 f32 of x (dead when PRE)
};

template<bool PRE>
__global__ __launch_bounds__(256, 2)
void q4k_gemm(const float* __restrict__ x, const ushort* __restrict__ xb,
              const int* __restrict__ qw, const float* __restrict__ bias,
              float* __restrict__ out)
{
  __shared__ ushort Ab[2][BM * BK];   // 16 KB each buf
  __shared__ ushort Bb[2][BN * BK];

  const int tid  = threadIdx.x;
  const int bid  = blockIdx.x;
  // XCD clustering: 4 m-tiles of one n-panel on the SAME xcd, adjacent bids
  const int xcd   = bid & 7;
  const int local = bid >> 3;                 // 0..63
  const int m0 = (local & 3) * BM;
  const int n0 = (xcd * 16 + (local >> 2)) * BN;

  const int sr = tid >> 2;   // staging row 0..63
  const int sq = tid & 3;    // staging quarter

  const int lane = tid & 63;
  const int wave = tid >> 6;
  const int wm = (wave >> 1) << 5;
  const int wn = (wave & 1) << 5;
  const int fr = lane & 15;
  const int fq = lane >> 4;

  const int c_sub = sq >> 1;        // which 64-k half within this BK step
  const int jq = (sq & 1) * 16;     // byte offset within the 32-byte qs group
  const int a0 = 8 * c_sub + (jq >> 3);   // first logical chunk this thread writes

  const int* bbase = qw + (n0 + sr) * (KB * 144);
  const float* aptr = PRE ? nullptr : (x + (m0 + sr) * Kdim + sq * 32);

  floatx4 acc[2][2] = {};
  BSet sA, sB;

  auto gloadB = [&](BSet& s, int t) {
    const int k0 = t * BK;
    const int* bp = bbase + (k0 >> 8) * 144;
    const int c  = ((k0 >> 6) & 3) + c_sub;
    const int jj = (2 * c) & 3;               // 0 or 2
    s.ddm = *(const uint4*)bp;
    s.D = *(const uint2*)(bp + 4 + jj);
    s.M = *(const uint2*)(bp + 8 + jj);
    s.X = *(const uint2*)(bp + 12 + jj);
    const int* qp = bp + 16 + c * 32 + jq;
    s.q[0] = *(const uint4*)(qp + 0);
    s.q[1] = *(const uint4*)(qp + 4);
    s.q[2] = *(const uint4*)(qp + 8);
    s.q[3] = *(const uint4*)(qp + 12);
    if (!PRE) {
      const float4* ap = (const float4*)(aptr + k0);
      #pragma unroll
      for (int i = 0; i < 8; ++i) s.av[i] = ap[i];
    }
  };

  auto gldsA = [&](int t, int buf) {
    if (PRE) {
      const int k0 = t * BK;
      #pragma unroll
      for (int q = 0; q < 4; ++q) {
        const int rloc = wave * 16 + q * 4 + (lane >> 4);
        const int chl  = (lane & 15) ^ (rloc & 15);   // pre-swizzled source
        const ushort* g = xb + (m0 + rloc) * Kdim + k0 + chl * 8;
        glds16((const void*)g, (void*)&Ab[buf][(wave * 16 + q * 4) * 128]);
      }
    }
  };

  auto stageB = [&](const BSet& s, int t, int buf) {
    const int c = (((t * BK) >> 6) & 3) + c_sub;
    const float d  = __half2float(__ushort_as_half(
        (ushort)((s.ddm.x & 255u) | ((s.ddm.y & 255u) << 8))));
    const float dm = __half2float(__ushort_as_half(
        (ushort)((s.ddm.z & 255u) | ((s.ddm.w & 255u) << 8))));
    const bool hi4 = (c >= 2);
    const uint sc0 = hi4 ? ((s.X.x & 15u) | ((s.D.x >> 2) & 48u)) : (s.D.x & 63u);
    const uint mn0 = hi4 ? ((s.X.x >> 4)  | ((s.M.x >> 2) & 48u)) : (s.M.x & 63u);
    const uint sc1 = hi4 ? ((s.X.y & 15u) | ((s.D.y >> 2) & 48u)) : (s.D.y & 63u);
    const uint mn1 = hi4 ? ((s.X.y >> 4)  | ((s.M.y >> 2) & 48u)) : (s.M.y & 63u);
    const float dl0 = d * (float)sc0, ml0 = dm * (float)mn0;
    const float dl1 = d * (float)sc1, ml1 = dm * (float)mn1;

    float wl[16], wh[16];
    #pragma unroll
    for (int i = 0; i < 4; ++i) {
      const uint4 qv = s.q[i];
      const uint b0 = qv.x, b1 = qv.y, b2 = qv.z, b3 = qv.w;
      wl[i*4+0] = fmaf(dl0, (float)(b0 & 15u), -ml0);
      wl[i*4+1] = fmaf(dl0, (float)(b1 & 15u), -ml0);
      wl[i*4+2] = fmaf(dl0, (float)(b2 & 15u), -ml0);
      wl[i*4+3] = fmaf(dl0, (float)(b3 & 15u), -ml0);
      wh[i*4+0] = fmaf(dl1, (float)(b0 >> 4),  -ml1);
      wh[i*4+1] = fmaf(dl1, (float)(b1 >> 4),  -ml1);
      wh[i*4+2] = fmaf(dl1, (float)(b2 >> 4),  -ml1);
      wh[i*4+3] = fmaf(dl1, (float)(b3 >> 4),  -ml1);
    }
    U8 u0, u1, u2, u3;
    #pragma unroll
    for (int p = 0; p < 4; ++p) {
      u0.u[p] = pk(wl[2*p],   wl[2*p+1]);
      u1.u[p] = pk(wl[8+2*p], wl[9+2*p]);
      u2.u[p] = pk(wh[2*p],   wh[2*p+1]);
      u3.u[p] = pk(wh[8+2*p], wh[9+2*p]);
    }
    *(bf16x8*)&Bb[buf][swz(sr, a0)]     = u0.v;
    *(bf16x8*)&Bb[buf][swz(sr, a0 + 1)] = u1.v;
    *(bf16x8*)&Bb[buf][swz(sr, a0 + 4)] = u2.v;
    *(bf16x8*)&Bb[buf][swz(sr, a0 + 5)] = u3.v;

    if (!PRE) {   // fallback A staging: 32 f32 -> bf16, chunks 4sq..4sq+3
      U8 xa[4];
      #pragma unroll
      for (int i = 0; i < 8; ++i) {
        xa[i >> 1].u[(i & 1) * 2]     = pk(s.av[i].x, s.av[i].y);
        xa[i >> 1].u[(i & 1) * 2 + 1] = pk(s.av[i].z, s.av[i].w);
      }
      #pragma unroll
      for (int g = 0; g < 4; ++g)
        *(bf16x8*)&Ab[buf][swz(sr, 4 * sq + g)] = xa[g].v;
    }
  };

  auto mfma_step = [&](int buf) {
    #pragma unroll
    for (int kk = 0; kk < 4; ++kk) {
      const bf16x8 af0 = *(const bf16x8*)&Ab[buf][swz(wm + fr,      kk*4 + fq)];
      const bf16x8 af1 = *(const bf16x8*)&Ab[buf][swz(wm + 16 + fr, kk*4 + fq)];
      const bf16x8 bf0 = *(const bf16x8*)&Bb[buf][swz(wn + fr,      kk*4 + fq)];
      const bf16x8 bf1 = *(const bf16x8*)&Bb[buf][swz(wn + 16 + fr, kk*4 + fq)];
      acc[0][0] = __builtin_amdgcn_mfma_f32_16x16x32_bf16(af0, bf0, acc[0][0], 0, 0, 0);
      acc[0][1] = __builtin_amdgcn_mfma_f32_16x16x32_bf16(af0, bf1, acc[0][1], 0, 0, 0);
      acc[1][0] = __builtin_amdgcn_mfma_f32_16x16x32_bf16(af1, bf0, acc[1][0], 0, 0, 0);
      acc[1][1] = __builtin_amdgcn_mfma_f32_16x16x32_bf16(af1, bf1, acc[1][1], 0, 0, 0);
    }
  };

  // prologue
  gloadB(sA, 0);
  gloadB(sB, 1);
  gldsA(0, 0);
  stageB(sA, 0, 0);
  __syncthreads();

  int curb = 0;
  for (int t = 0; t < NT; t += 2) {
    // substep even: compute t, prep t+1, prefetch t+2
    if (t + 2 < NT) gloadB(sA, t + 2);
    gldsA(t + 1, curb ^ 1);
    __builtin_amdgcn_sched_barrier(0);
    mfma_step(curb);
    stageB(sB, t + 1, curb ^ 1);
    __syncthreads();
    curb ^= 1;
    // substep odd: compute t+1, prep t+2, prefetch t+3
    if (t + 3 < NT) gloadB(sB, t + 3);
    if (t + 2 < NT) gldsA(t + 2, curb ^ 1);
    __builtin_amdgcn_sched_barrier(0);
    mfma_step(curb);
    if (t + 2 < NT) stageB(sA, t + 2, curb ^ 1);
    __syncthreads();
    curb ^= 1;
  }

  // epilogue: C/D layout col=lane&15, row=(lane>>4)*4+reg
  #pragma unroll
  for (int mi = 0; mi < 2; ++mi) {
    #pragma unroll
    for (int ni = 0; ni < 2; ++ni) {
      const int gn = n0 + wn + ni * 16 + fr;
      const float bv = bias[gn];
      #pragma unroll
      for (int jj = 0; jj < 4; ++jj) {
        const int gm = m0 + wm + mi * 16 + fq * 4 + jj;
        out[gm * Ndim + gn] = acc[mi][ni][jj] + bv;
      }
    }
  }
}

// one-shot x (f32) -> bf16 into workspace
__global__ __launch_bounds__(256)
void cvt_x_bf16(const float* __restrict__ x, ushort* __restrict__ xb) {
  const int i = blockIdx.x * blockDim.x + threadIdx.x;   // 8 elems each
  const float4* p = (const float4*)x + i * 2;
  const float4 a = p[0], b = p[1];
  U8 u;
  u.u[0] = pk(a.x, a.y); u.u[1] = pk(a.z, a.w);
  u.u[2] = pk(b.x, b.y); u.u[3] = pk(b.z, b.w);
  *(bf16x8*)(xb + i * 8) = u.v;
}

extern "C" void kernel_launch(void* const* d_in, const int* in_sizes, int n_in,
                              void* d_out, int out_size, void* d_ws, size_t ws_size,
                              hipStream_t stream) {
  const float* x    = (const float*)d_in[0];
  const int*   qw   = (const int*)d_in[1];
  const float* bias = (const float*)d_in[2];
  float* out = (float*)d_out;

  const size_t need = (size_t)Mdim * Kdim * sizeof(ushort);   // 4 MB
  if (ws_size >= need) {
    ushort* xb = (ushort*)d_ws;
    cvt_x_bf16<<<(Mdim * Kdim / 8) / 256, 256, 0, stream>>>(x, xb);
    q4k_gemm<true><<<512, 256, 0, stream>>>(x, xb, qw, bias, out);
  } else {
    q4k_gemm<false><<<512, 256, 0, stream>>>(x, nullptr, qw, bias, out);
  }
}

// Round 3
// 82.050 us; speedup vs baseline: 2.2449x; 1.3528x over previous
//
#include <hip/hip_runtime.h>
#include <hip/hip_fp16.h>

typedef __bf16 bf16x8 __attribute__((ext_vector_type(8)));
typedef float floatx16 __attribute__((ext_vector_type(16)));
typedef unsigned int uint;
typedef unsigned short ushort;

constexpr int Mdim = 256, Ndim = 8192, Kdim = 8192;
constexpr int BN = 32, BK = 64, KSPLIT = 4;
constexpr int KS = Kdim / KSPLIT;    // 2048 per block
constexpr int NT = KS / BK;          // 32 K-steps
constexpr int KB = Kdim / 256;       // 32 q4k blocks per weight row

union UB { uint u[4]; bf16x8 v; };

__device__ __forceinline__ uint cvtpk(float lo, float hi) {
  uint r; asm("v_cvt_pk_bf16_f32 %0, %1, %2" : "=v"(r) : "v"(lo), "v"(hi));
  return r;
}

// B LDS: 32 rows x 64 ushort (128B row); XOR-swizzle 16B chunks across banks
__device__ __forceinline__ int bswz(int row, int ch) {
  return row * 64 + ((ch ^ (row & 7)) << 3);
}

template<bool PRE>
__global__ __launch_bounds__(256, 4)
void q4k_gemm(const float* __restrict__ x, const bf16x8* __restrict__ xbf,
              const int* __restrict__ qw, const float* __restrict__ bias,
              float* __restrict__ out)
{
  __shared__ ushort Bb[BN * 64];   // 4 KB, single-buffered (reg-staged)

  const int tid = threadIdx.x;
  const int bid = blockIdx.x;
  // bijective XCD swizzle: the 4 ks-siblings of one n-tile share an XCD
  const int l  = (bid & 7) * 128 + (bid >> 3);
  const int nb = l >> 2;
  const int ks = l & 3;
  const int n0 = nb * BN;
  const int ks8 = ks * (KS >> 8);

  const int sr = tid >> 3;   // B row 0..31
  const int sq = tid & 7;    // byte-quad within 32B qs group

  const int lane = tid & 63;
  const int wave = tid >> 6;
  const int mb0  = wave * 2;       // two 32-row m-frags per wave
  const int brow = lane & 31;
  const int bco  = lane >> 5;

  const int* bp0 = qw + (n0 + sr) * (KB * 144);

  uint4 R[2];
  uint4 Mdd[2], M0[2], M1[2], M2[2];
  uint2 pq0, pq1;
  floatx16 acc0 = {}, acc1 = {};

  auto gload = [&](int s2, int rs, int ms, bool meta) {
    const int* bp = bp0 + (ks8 + (s2 >> 2)) * 144;
    R[rs] = *(const uint4*)(bp + 16 + (s2 & 3) * 32 + sq * 4);
    if (meta) {
      Mdd[ms] = *(const uint4*)bp;
      M0[ms]  = *(const uint4*)(bp + 4);
      M1[ms]  = *(const uint4*)(bp + 8);
      M2[ms]  = *(const uint4*)(bp + 12);
    }
  };

  auto dequant = [&](int c, int rs, int ms) {
    const uint4 dd = Mdd[ms];
    const float d  = __half2float(__ushort_as_half((ushort)((dd.x & 255u) | ((dd.y & 255u) << 8))));
    const float dm = __half2float(__ushort_as_half((ushort)((dd.z & 255u) | ((dd.w & 255u) << 8))));
    const uint4 s0 = M0[ms], s1 = M1[ms], s2 = M2[ms];
    uint scA, scB, mnA, mnB;
    if (c == 0)      { scA = s0.x & 63u; scB = s0.y & 63u; mnA = s1.x & 63u; mnB = s1.y & 63u; }
    else if (c == 1) { scA = s0.z & 63u; scB = s0.w & 63u; mnA = s1.z & 63u; mnB = s1.w & 63u; }
    else if (c == 2) {
      scA = (s2.x & 15u) | ((s0.x >> 2) & 48u); scB = (s2.y & 15u) | ((s0.y >> 2) & 48u);
      mnA = (s2.x >> 4)  | ((s1.x >> 2) & 48u); mnB = (s2.y >> 4)  | ((s1.y >> 2) & 48u);
    } else {
      scA = (s2.z & 15u) | ((s0.z >> 2) & 48u); scB = (s2.w & 15u) | ((s0.w >> 2) & 48u);
      mnA = (s2.z >> 4)  | ((s1.z >> 2) & 48u); mnB = (s2.w >> 4)  | ((s1.w >> 2) & 48u);
    }
    const float dlA = d * (float)scA, mlA = dm * (float)mnA;
    const float dlB = d * (float)scB, mlB = dm * (float)mnB;
    const uint4 qv = R[rs];
    const float w0 = fmaf(dlA, (float)(qv.x & 15u), -mlA);
    const float w1 = fmaf(dlA, (float)(qv.y & 15u), -mlA);
    const float w2 = fmaf(dlA, (float)(qv.z & 15u), -mlA);
    const float w3 = fmaf(dlA, (float)(qv.w & 15u), -mlA);
    const float h0 = fmaf(dlB, (float)(qv.x >> 4), -mlB);
    const float h1 = fmaf(dlB, (float)(qv.y >> 4), -mlB);
    const float h2 = fmaf(dlB, (float)(qv.z >> 4), -mlB);
    const float h3 = fmaf(dlB, (float)(qv.w >> 4), -mlB);
    pq0.x = cvtpk(w0, w1); pq0.y = cvtpk(w2, w3);
    pq1.x = cvtpk(h0, h1); pq1.y = cvtpk(h2, h3);
  };

  auto bwrite = [&]() {
    *(uint2*)&Bb[bswz(sr, (sq >> 1))     + (sq & 1) * 4] = pq0;
    *(uint2*)&Bb[bswz(sr, 4 + (sq >> 1)) + (sq & 1) * 4] = pq1;
  };

  auto mstep = [&](int s) {
    const int kb = (ks * KS + s * BK) >> 4;     // global k16-block index
    const bf16x8* a0p = PRE ? (xbf + ((mb0    ) * 512 + kb) * 64 + lane) : nullptr;
    const bf16x8* a1p = PRE ? (xbf + ((mb0 + 1) * 512 + kb) * 64 + lane) : nullptr;
    #pragma unroll
    for (int kk = 0; kk < 4; ++kk) {
      const bf16x8 bq = *(const bf16x8*)&Bb[bswz(brow, kk * 2 + bco)];
      bf16x8 a0, a1;
      if (PRE) {
        a0 = a0p[kk * 64];
        a1 = a1p[kk * 64];
      } else {
        const int kg = ks * KS + s * BK + kk * 16 + bco * 8;
        const float4* fA = (const float4*)(x + (mb0 * 32 + brow) * Kdim + kg);
        const float4* fB = (const float4*)(x + ((mb0 + 1) * 32 + brow) * Kdim + kg);
        const float4 p0 = fA[0], p1 = fA[1], q0 = fB[0], q1 = fB[1];
        UB ua, ub;
        ua.u[0] = cvtpk(p0.x, p0.y); ua.u[1] = cvtpk(p0.z, p0.w);
        ua.u[2] = cvtpk(p1.x, p1.y); ua.u[3] = cvtpk(p1.z, p1.w);
        ub.u[0] = cvtpk(q0.x, q0.y); ub.u[1] = cvtpk(q0.z, q0.w);
        ub.u[2] = cvtpk(q1.x, q1.y); ub.u[3] = cvtpk(q1.z, q1.w);
        a0 = ua.v; a1 = ub.v;
      }
      acc0 = __builtin_amdgcn_mfma_f32_32x32x16_bf16(a0, bq, acc0, 0, 0, 0);
      acc1 = __builtin_amdgcn_mfma_f32_32x32x16_bf16(a1, bq, acc1, 0, 0, 0);
    }
  };

  // prologue: stage step 0, prefetch step 1
  gload(0, 0, 0, true);
  gload(1, 1, 0, false);
  dequant(0, 0, 0);
  bwrite();
  __syncthreads();

  #define PH(u) {                                                          \
    const int s_ = base + (u);                                             \
    if (s_ + 2 < NT) gload(s_ + 2, (u) & 1, (((u) + 2) >> 2) & 1,          \
                           (((u) + 2) & 3) == 0);                          \
    if (s_ + 1 < NT) dequant(((u) + 1) & 3, ((u) + 1) & 1,                 \
                             (((u) + 1) >> 2) & 1);                        \
    mstep(s_);                                                             \
    __syncthreads();                                                       \
    if (s_ + 1 < NT) bwrite();                                             \
    __syncthreads();                                                       \
  }

  for (int base = 0; base < NT; base += 8) {
    PH(0) PH(1) PH(2) PH(3) PH(4) PH(5) PH(6) PH(7)
  }
  #undef PH

  // epilogue: D layout col=lane&31, row=(r&3)+8*(r>>2)+4*(lane>>5)  [m74/m101]
  const int gn = n0 + (lane & 31);
  const float bv = (ks == 0) ? bias[gn] : 0.0f;
  const int mrow = wave * 64 + 4 * (lane >> 5);
  #pragma unroll
  for (int r = 0; r < 16; ++r) {
    const int m = mrow + (r & 3) + 8 * (r >> 2);
    atomicAdd(&out[m * Ndim + gn], acc0[r] + bv);
  }
  #pragma unroll
  for (int r = 0; r < 16; ++r) {
    const int m = mrow + 32 + (r & 3) + 8 * (r >> 2);
    atomicAdd(&out[m * Ndim + gn], acc1[r] + bv);
  }
}

// zero d_out (atomic accumulate target) and optionally pre-tile x -> bf16
// MFMA-fragment layout: xb[(mb*512+kb)*64+lane] = 16B frag slice,
// m = mb*32+(lane&31), k = kb*16+(lane>>5)*8
template<bool DOCVT>
__global__ __launch_bounds__(256)
void prep(const float* __restrict__ x, uint4* __restrict__ xb,
          float4* __restrict__ out)
{
  const int gid = blockIdx.x * 256 + threadIdx.x;
  out[gid * 2]     = float4{0.f, 0.f, 0.f, 0.f};
  out[gid * 2 + 1] = float4{0.f, 0.f, 0.f, 0.f};
  if (DOCVT) {
    const int lane = gid & 63;
    const int m = ((gid >> 15) * 32) + (lane & 31);
    const int k = (((gid >> 6) & 511) * 16) + (lane >> 5) * 8;
    const float4* p = (const float4*)(x + m * Kdim + k);
    const float4 f0 = p[0], f1 = p[1];
    uint4 st;
    st.x = cvtpk(f0.x, f0.y); st.y = cvtpk(f0.z, f0.w);
    st.z = cvtpk(f1.x, f1.y); st.w = cvtpk(f1.z, f1.w);
    xb[gid] = st;
  }
}

extern "C" void kernel_launch(void* const* d_in, const int* in_sizes, int n_in,
                              void* d_out, int out_size, void* d_ws, size_t ws_size,
                              hipStream_t stream) {
  (void)in_sizes; (void)n_in; (void)out_size;
  const float* x    = (const float*)d_in[0];
  const int*   qw   = (const int*)d_in[1];
  const float* bias = (const float*)d_in[2];
  float* out = (float*)d_out;

  const size_t need = (size_t)Mdim * Kdim * 2;   // 4 MB bf16 fragment tiles
  if (ws_size >= need) {
    prep<true><<<1024, 256, 0, stream>>>(x, (uint4*)d_ws, (float4*)out);
    q4k_gemm<true><<<1024, 256, 0, stream>>>(x, (const bf16x8*)d_ws, qw, bias, out);
  } else {
    prep<false><<<1024, 256, 0, stream>>>(x, nullptr, (float4*)out);
    q4k_gemm<false><<<1024, 256, 0, stream>>>(x, nullptr, qw, bias, out);
  }
}